// Round 12
// baseline (6660.326 us; speedup 1.0000x reference)
//
#include <hip/hip_runtime.h>

typedef short bf16x8 __attribute__((ext_vector_type(8)));
typedef float f32x4 __attribute__((ext_vector_type(4)));
typedef unsigned u32x4 __attribute__((ext_vector_type(4)));

#define T_STEPS 1024
#define NBATCH  64
#define HID     1024
#define NIN     27
#define RINGN   32
#define LAG     8
#define BPG     16
#define NWG     128     // 4 groups x 32 j-slices
#define WGSZ    512     // 8 waves

#define RINGHI_BYTES ((size_t)RINGN * NBATCH * HID * 2)   // 4 MiB
#define FLAGS_INTS   (NWG * 16)                           // per-WG flags, 64B stride
#define FLAGS_BYTES  ((size_t)FLAGS_INTS * sizeof(int))   // 8 KiB
#define WS_NEED      (RINGHI_BYTES + FLAGS_BYTES)

__device__ __forceinline__ unsigned short f2bf(float f) {
    unsigned u = __float_as_uint(f);
    unsigned r = u + 0x7FFFu + ((u >> 16) & 1u);
    return (unsigned short)(r >> 16);
}
__device__ __forceinline__ float bf2f(unsigned short h) {
    return __uint_as_float(((unsigned)h) << 16);
}

// ---- system-coherent (cross-XCD) ops -- the R3-R5/R10-proven primitives ----
__device__ __forceinline__ void ld_b128_sys(const void* p, u32x4& v) {
    asm volatile("global_load_dwordx4 %0, %1, off sc0 sc1" : "=v"(v) : "v"(p));
}
__device__ __forceinline__ void ld_b32_sys(const void* p, unsigned& v) {
    asm volatile("global_load_dword %0, %1, off sc0 sc1" : "=v"(v) : "v"(p));
}
__device__ __forceinline__ int ld_flag_sys(const int* p) {
    int v;
    asm volatile("global_load_dword %0, %1, off sc0 sc1\n\ts_waitcnt vmcnt(0)"
                 : "=v"(v) : "v"(p) : "memory");
    return v;
}
__device__ __forceinline__ void st_b32_sys(void* p, unsigned v) {
    asm volatile("global_store_dword %0, %1, off sc0 sc1" :: "v"(p), "v"(v) : "memory");
}
__device__ __forceinline__ void wait_vm0() {
    asm volatile("s_waitcnt vmcnt(0)" ::: "memory");
    __builtin_amdgcn_sched_barrier(0);   // rule #18: pin consumers below the wait
}

// Persistent GRU, 8-wave WGs to halve the per-wave serial load chain:
// 4 groups x 32 WGs(512thr). Group gb owns batches [16gb,16gb+16); WG gs owns
// hidden cols [32gs,32gs+32). Wave kq owns K-eighth [128kq,+128) -> 4 b128
// ring loads/wave/step. W_hh slice (96 VGPR/lane) register-resident; h exact
// fp32 per thread; single bf16 ring (doubles as y_hat history for decode).
// Sync: R10's proven per-WG flags; consumer wave polls its 4 producer WGs.
__global__ __launch_bounds__(WGSZ, 1)
void gru_persist(const float* __restrict__ x,
                 const int* __restrict__ delays,
                 const float* __restrict__ W_ih,
                 const float* __restrict__ W_hh,
                 const float* __restrict__ b_ih,
                 const float* __restrict__ b_hh,
                 const float* __restrict__ W_dec,
                 float* __restrict__ out,
                 unsigned short* __restrict__ ring_hi,
                 int* __restrict__ flags)
{
    const int tid  = threadIdx.x;
    const int lane = tid & 63;
    const int kq   = tid >> 6;          // wave id = K-eighth (0..7)
    const int gb   = blockIdx.x >> 5;   // batch group (0..3)
    const int gs   = blockIdx.x & 31;   // j-slice (0..31)
    const int j0   = gs * 32;
    const int l15  = lane & 15;
    const int lhi  = lane >> 4;
    const int Bg   = gb * BPG;

    __shared__ f32x4 red[48 * 64];      // [gate(3)xct(2)xwave(8)][lane]
    __shared__ f32x4 inx[2 * 64];       // i_n x-part per col-tile (wave 0)
    __shared__ float ylds[2][512];      // decode y half-row, parity-buffered
    __shared__ float decp[256];         // decode partials [wave][o]
    __shared__ float bias_lds[128];

    // ---- persistent W_hh bf16 fragments: 3 gates x 2 col-tiles x 4 K-chunks
    bf16x8 wHH[3][2][4];
    #pragma unroll
    for (int n = 0; n < 3; ++n)
        #pragma unroll
        for (int ct = 0; ct < 2; ++ct) {
            const float* wrow = W_hh + (size_t)(n * HID + j0 + ct * 16 + l15) * HID;
            #pragma unroll
            for (int c = 0; c < 4; ++c) {
                const float* wr = wrow + kq * 128 + c * 32 + lhi * 8;
                #pragma unroll
                for (int jj = 0; jj < 8; ++jj) wHH[n][ct][c][jj] = (short)f2bf(wr[jj]);
            }
        }
    bf16x8 wXH[3][2];
    #pragma unroll
    for (int n = 0; n < 3; ++n)
        #pragma unroll
        for (int ct = 0; ct < 2; ++ct) {
            const float* wrow = W_ih + (size_t)(n * HID + j0 + ct * 16 + l15) * NIN;
            #pragma unroll
            for (int jj = 0; jj < 8; ++jj) {
                const int kk = lhi * 8 + jj;
                wXH[n][ct][jj] = (kk < NIN) ? (short)f2bf(wrow[kk]) : (short)0;
            }
        }
    if (tid < 32) {
        bias_lds[tid]      = b_ih[j0 + tid] + b_hh[j0 + tid];               // r
        bias_lds[32 + tid] = b_ih[HID + j0 + tid] + b_hh[HID + j0 + tid];   // z
        bias_lds[64 + tid] = b_ih[2 * HID + j0 + tid];                      // n (x side)
        bias_lds[96 + tid] = b_hh[2 * HID + j0 + tid];                      // n (h side)
    }
    // ---- fused decode: 2 WGs per batch, 512 cols each ----
    const int bdec  = Bg + (gs >> 1);
    const int qdec  = gs & 1;
    const int d_del = delays[bdec];
    const int odec  = tid & 31;
    const int jgd   = tid >> 5;         // 0..15 -> cols [jgd*32, +32)
    float wd[32];
    #pragma unroll
    for (int jj = 0; jj < 32; ++jj)
        wd[jj] = (odec < NIN) ? W_dec[(size_t)odec * HID + qdec * 512 + jgd * 32 + jj] : 0.f;

    const int bl = tid >> 5;            // gate thread: batch-in-group (0..15)
    const int jc = tid & 31;            // gate thread: col-in-slice (0..31)
    const int arow = Bg + l15;          // A-fragment row = batch-in-group
    const unsigned* ringdw = (const unsigned*)ring_hi;

    int* myflag = flags + blockIdx.x * 16;
    // wave kq consumes cols [128kq,+128) = producer WGs 4kq..4kq+3
    const int* pollflag = flags + (gb * 32 + kq * 4 + (lane & 3)) * 16;

    float hprev = 0.f;
    bool dead = false;

    __syncthreads();

    #pragma clang loop unroll(disable)
    for (int t = 0; t < T_STEPS + LAG; ++t) {
        const int target = (t < T_STEPS) ? t : T_STEPS;
        const int t_dec  = t - LAG;
        const int slot_prev = (t + RINGN - 1) & (RINGN - 1);

        // ---- (A) decode y-row load: data >=7 steps old, long visible
        unsigned ydw = 0;
        if (t_dec >= 0 && tid < 256) {
            const int tau = (t_dec < d_del) ? t_dec : (t_dec - d_del);
            const unsigned* yrow = ringdw
                + ((size_t)((tau & (RINGN - 1)) * NBATCH + bdec)) * (HID / 2) + qdec * 256;
            ld_b32_sys(yrow + tid, ydw);
        }
        // ---- (B) x fragments (wave 0): independent of h
        bf16x8 axH = {}, axL = {};
        if (t < T_STEPS && kq == 0) {
            const float* xr = x + ((size_t)arow * T_STEPS + t) * NIN;
            #pragma unroll
            for (int jj = 0; jj < 8; ++jj) {
                const int kk = lhi * 8 + jj;
                if (kk < NIN) {
                    float f = xr[kk];
                    unsigned short hi = f2bf(f);
                    axH[jj] = (short)hi;
                    axL[jj] = (short)f2bf(f - bf2f(hi));
                }
            }
        }
        __builtin_amdgcn_sched_barrier(0);   // compiler x-waits stay above

        // ---- (C) poll: 4 lanes watch this wave's 4 producer WGs
        if (target > 0 && !dead) {
            int iter = 0;
            for (;;) {
                int v = target;
                if (lane < 4) v = ld_flag_sys(pollflag);
                if (__all(v >= target)) break;
                if (++iter > (1 << 16)) { dead = true; break; }
            }
        }
        wait_vm0();   // free if poll ran; covers t==0 / y / x stragglers

        // ---- (D) 4 ring loads (K-eighth), x-MFMAs overlap under them
        u32x4 rawH[4];
        if (t < T_STEPS) {
            const unsigned short* aH = ring_hi + ((size_t)(slot_prev * NBATCH + arow)) * HID
                                     + kq * 128 + lhi * 8;
            #pragma unroll
            for (int c = 0; c < 4; ++c) ld_b128_sys(aH + c * 32, rawH[c]);
        }

        f32x4 z4 = {0.f, 0.f, 0.f, 0.f};
        f32x4 acc[3][2] = {{z4, z4}, {z4, z4}, {z4, z4}};
        f32x4 accx[2] = {z4, z4};

        if (t < T_STEPS) {
            if (kq == 0) {              // x-path: 12 MFMAs while ring loads fly
                #pragma unroll
                for (int ct = 0; ct < 2; ++ct) {
                    acc[0][ct] = __builtin_amdgcn_mfma_f32_16x16x32_bf16(axH, wXH[0][ct], acc[0][ct], 0, 0, 0);
                    acc[1][ct] = __builtin_amdgcn_mfma_f32_16x16x32_bf16(axH, wXH[1][ct], acc[1][ct], 0, 0, 0);
                    accx[ct]   = __builtin_amdgcn_mfma_f32_16x16x32_bf16(axH, wXH[2][ct], accx[ct], 0, 0, 0);
                    acc[0][ct] = __builtin_amdgcn_mfma_f32_16x16x32_bf16(axL, wXH[0][ct], acc[0][ct], 0, 0, 0);
                    acc[1][ct] = __builtin_amdgcn_mfma_f32_16x16x32_bf16(axL, wXH[1][ct], acc[1][ct], 0, 0, 0);
                    accx[ct]   = __builtin_amdgcn_mfma_f32_16x16x32_bf16(axL, wXH[2][ct], accx[ct], 0, 0, 0);
                }
            }
            wait_vm0();                 // the 4 h loads done
            #pragma unroll
            for (int c = 0; c < 4; ++c) {       // W . h : 24 MFMAs
                bf16x8 a = __builtin_bit_cast(bf16x8, rawH[c]);
                #pragma unroll
                for (int ct = 0; ct < 2; ++ct) {
                    acc[0][ct] = __builtin_amdgcn_mfma_f32_16x16x32_bf16(a, wHH[0][ct][c], acc[0][ct], 0, 0, 0);
                    acc[1][ct] = __builtin_amdgcn_mfma_f32_16x16x32_bf16(a, wHH[1][ct][c], acc[1][ct], 0, 0, 0);
                    acc[2][ct] = __builtin_amdgcn_mfma_f32_16x16x32_bf16(a, wHH[2][ct][c], acc[2][ct], 0, 0, 0);
                }
            }
            #pragma unroll
            for (int n = 0; n < 3; ++n)
                #pragma unroll
                for (int ct = 0; ct < 2; ++ct)
                    red[((n * 2 + ct) * 8 + kq) * 64 + lane] = acc[n][ct];
            if (kq == 0) {
                inx[0 * 64 + lane] = accx[0];
                inx[1 * 64 + lane] = accx[1];
            }
        } else {
            wait_vm0();                 // drain y loads in tail steps
        }
        if (t_dec >= 0 && tid < 256) {
            ylds[t & 1][2 * tid]     = bf2f((unsigned short)(ydw & 0xFFFFu));
            ylds[t & 1][2 * tid + 1] = bf2f((unsigned short)(ydw >> 16));
        }
        __syncthreads();   // sync1

        if (t < T_STEPS) {
            // reduce 8 K-eighth partials; C layout: col=lane&15, row=(lane>>4)*4+reg
            const int ct   = jc >> 4;
            const int c16  = jc & 15;
            const int ridx = (c16 + 16 * (bl >> 2)) * 4 + (bl & 3);
            const float* redf = (const float*)red;
            float gr = 0.f, gz = 0.f, gh_n = 0.f;
            #pragma unroll
            for (int w = 0; w < 8; ++w) {
                gr   += redf[((0 * 2 + ct) * 8 + w) * 256 + ridx];
                gz   += redf[((1 * 2 + ct) * 8 + w) * 256 + ridx];
                gh_n += redf[((2 * 2 + ct) * 8 + w) * 256 + ridx];
            }
            const float i_n = ((const float*)inx)[ct * 256 + ridx];
            const float r  = 1.f / (1.f + __expf(-(gr + bias_lds[jc])));
            const float z  = 1.f / (1.f + __expf(-(gz + bias_lds[32 + jc])));
            const float nn = tanhf(i_n + bias_lds[64 + jc] + r * (gh_n + bias_lds[96 + jc]));
            const float hnew = (1.f - z) * nn + z * hprev;
            hprev = hnew;
            // pack adjacent-col pair into one dword (even-jc threads store)
            const unsigned short hih = f2bf(hnew);
            const unsigned nhi = __shfl_xor((unsigned)hih, 1);
            if ((jc & 1) == 0) {
                const unsigned dhi = (unsigned)hih | (nhi << 16);
                const int bg = Bg + bl;
                unsigned* ph = (unsigned*)ring_hi
                    + ((size_t)((t & (RINGN - 1)) * NBATCH + bg)) * (HID / 2)
                    + ((j0 + jc) >> 1);
                st_b32_sys(ph, dhi);
            }
        }
        // decode MACs hide here (post-store, pre-drain)
        if (t_dec >= 0) {
            float p = 0.f;
            if (odec < NIN) {
                const float* yrow = ylds[t & 1] + jgd * 32;
                #pragma unroll
                for (int k = 0; k < 32; ++k) p += yrow[k] * wd[k];
            }
            p += __shfl_xor(p, 32);     // fold the wave's two j-groups
            if (lane < 32) decp[kq * 32 + (lane & 31)] = p;
        }
        wait_vm0();        // drain own h stores to the coherent point
        __syncthreads();   // sync2: whole WG's h globally visible, decp ready

        if (t < T_STEPS && tid == 0 && !dead)
            st_b32_sys(myflag, (unsigned)(t + 1));

        // ---- tail (shadowed by other WGs' polls): decode atomics
        if (t_dec >= 0 && tid < NIN) {
            float v = 0.f;
            #pragma unroll
            for (int w = 0; w < 8; ++w) v += decp[w * 32 + tid];
            atomicAdd(out + ((size_t)bdec * T_STEPS + t_dec) * NIN + tid, v);
        }
    }
}

__global__ void fill_out_kernel(float* __restrict__ out, const float* __restrict__ b_dec, int n)
{
    int idx = blockIdx.x * blockDim.x + threadIdx.x;
    if (idx < n) out[idx] = b_dec[idx % NIN];
}

extern "C" void kernel_launch(void* const* d_in, const int* in_sizes, int n_in,
                              void* d_out, int out_size, void* d_ws, size_t ws_size,
                              hipStream_t stream)
{
    (void)in_sizes; (void)n_in;
    const float* xx    = (const float*)d_in[0];
    const int*   dl    = (const int*)d_in[1];
    const float* W_ih  = (const float*)d_in[2];
    const float* W_hh  = (const float*)d_in[3];
    const float* b_ih  = (const float*)d_in[4];
    const float* b_hh  = (const float*)d_in[5];
    const float* W_dec = (const float*)d_in[6];
    const float* b_dec = (const float*)d_in[7];
    float* out = (float*)d_out;

    if (ws_size < WS_NEED) return;

    unsigned short* ring_hi = (unsigned short*)d_ws;
    int*            flags   = (int*)((char*)d_ws + RINGHI_BYTES);

    const size_t slot_bytes = (size_t)NBATCH * HID * 2;   // 128 KiB
    // zero h(-1) (ring slot 31) + flags -- contiguous tail region
    hipMemsetAsync((char*)d_ws + (size_t)(RINGN - 1) * slot_bytes, 0,
                   slot_bytes + FLAGS_BYTES, stream);

    fill_out_kernel<<<dim3((out_size + 255) / 256), dim3(256), 0, stream>>>(out, b_dec, out_size);

    void* args[] = {(void*)&xx, (void*)&dl, (void*)&W_ih, (void*)&W_hh, (void*)&b_ih,
                    (void*)&b_hh, (void*)&W_dec, (void*)&out, (void*)&ring_hi, (void*)&flags};
    hipError_t e = hipLaunchCooperativeKernel((void*)gru_persist, dim3(NWG), dim3(WGSZ),
                                              args, 0, stream);
    if (e != hipSuccess) {
        gru_persist<<<dim3(NWG), dim3(WGSZ), 0, stream>>>(xx, dl, W_ih, W_hh, b_ih, b_hh,
                                                          W_dec, out, ring_hi, flags);
    }
}

// Round 13
// 4722.289 us; speedup vs baseline: 1.4104x; 1.4104x over previous
//
#include <hip/hip_runtime.h>

typedef short bf16x8 __attribute__((ext_vector_type(8)));
typedef float f32x4 __attribute__((ext_vector_type(4)));
typedef unsigned u32x4 __attribute__((ext_vector_type(4)));

#define T_STEPS 1024
#define NBATCH  64
#define HID     1024
#define NIN     27
#define RINGN   32
#define LAG     8
#define BPG     16
#define NWG     128     // 4 groups x 32 j-slices (JT=32)
#define JT      32

#define RINGHI_BYTES ((size_t)RINGN * NBATCH * HID * 2)   // 4 MiB
#define FLAGS_INTS   (NWG * 16)                           // per-WG flags, 64B stride
#define FLAGS_BYTES  ((size_t)FLAGS_INTS * sizeof(int))   // 8 KiB
#define WS_NEED      (RINGHI_BYTES + FLAGS_BYTES)

__device__ __forceinline__ unsigned short f2bf(float f) {
    unsigned u = __float_as_uint(f);
    unsigned r = u + 0x7FFFu + ((u >> 16) & 1u);
    return (unsigned short)(r >> 16);
}
__device__ __forceinline__ float bf2f(unsigned short h) {
    return __uint_as_float(((unsigned)h) << 16);
}

// ---- system-coherent (cross-XCD) ops -- the R3-R5/R10-proven primitives ----
__device__ __forceinline__ void ld_b128_sys(const void* p, u32x4& v) {
    asm volatile("global_load_dwordx4 %0, %1, off sc0 sc1" : "=v"(v) : "v"(p));
}
__device__ __forceinline__ void ld_b32_sys(const void* p, unsigned& v) {
    asm volatile("global_load_dword %0, %1, off sc0 sc1" : "=v"(v) : "v"(p));
}
__device__ __forceinline__ int ld_flag_sys(const int* p) {
    int v;
    asm volatile("global_load_dword %0, %1, off sc0 sc1\n\ts_waitcnt vmcnt(0)"
                 : "=v"(v) : "v"(p) : "memory");
    return v;
}
__device__ __forceinline__ void st_b32_sys(void* p, unsigned v) {
    asm volatile("global_store_dword %0, %1, off sc0 sc1" :: "v"(p), "v"(v) : "memory");
}
__device__ __forceinline__ void wait_vm0() {
    asm volatile("s_waitcnt vmcnt(0)" ::: "memory");
    __builtin_amdgcn_sched_barrier(0);   // rule #18: pin consumers below the wait
}

// Persistent GRU (R10 structure, JT=32 to halve the LLC broadcast):
// 4 groups x 32 WGs(256thr). Group gb owns batches [16gb,16gb+16); WG gs owns
// hidden cols [32gs,32gs+32) as 2 col-tiles. Wave kq = K-quarter: 8 b128 ring
// loads + 48 MFMAs. W_hh slice (192 VGPR/lane) register-resident; h exact fp32
// per thread; single bf16 ring (doubles as y_hat history for fused decode).
// Chip-wide broadcast: 128 WGs x 32KB = 4 MB/step (was 8 MB at JT=16).
__global__ __launch_bounds__(256, 1)
void gru_persist(const float* __restrict__ x,
                 const int* __restrict__ delays,
                 const float* __restrict__ W_ih,
                 const float* __restrict__ W_hh,
                 const float* __restrict__ b_ih,
                 const float* __restrict__ b_hh,
                 const float* __restrict__ W_dec,
                 float* __restrict__ out,
                 unsigned short* __restrict__ ring_hi,
                 int* __restrict__ flags)
{
    const int tid  = threadIdx.x;
    const int lane = tid & 63;
    const int kq   = tid >> 6;          // wave id = K-quarter (0..3)
    const int gb   = blockIdx.x >> 5;   // batch group (0..3)
    const int gs   = blockIdx.x & 31;   // j-slice (0..31)
    const int j0   = gs * JT;
    const int l15  = lane & 15;
    const int lhi  = lane >> 4;
    const int Bg   = gb * BPG;

    __shared__ f32x4 red[26 * 64];      // 24 = 3 gates x 2 ct x 4 waves, +2 = i_n x-part
    __shared__ float ylds[2][512];      // decode y half-row, parity-buffered
    __shared__ float bias_lds[128];

    // ---- persistent W_hh bf16 fragments: 3 gates x 2 col-tiles x 8 K-chunks
    bf16x8 wHH[3][2][8];
    #pragma unroll
    for (int n = 0; n < 3; ++n)
        #pragma unroll
        for (int ct = 0; ct < 2; ++ct) {
            const float* wrow = W_hh + (size_t)(n * HID + j0 + ct * 16 + l15) * HID;
            #pragma unroll
            for (int c = 0; c < 8; ++c) {
                const float* wr = wrow + kq * 256 + c * 32 + lhi * 8;
                #pragma unroll
                for (int jj = 0; jj < 8; ++jj) wHH[n][ct][c][jj] = (short)f2bf(wr[jj]);
            }
        }
    bf16x8 wXH[3][2];
    #pragma unroll
    for (int n = 0; n < 3; ++n)
        #pragma unroll
        for (int ct = 0; ct < 2; ++ct) {
            const float* wrow = W_ih + (size_t)(n * HID + j0 + ct * 16 + l15) * NIN;
            #pragma unroll
            for (int jj = 0; jj < 8; ++jj) {
                const int kk = lhi * 8 + jj;
                wXH[n][ct][jj] = (kk < NIN) ? (short)f2bf(wrow[kk]) : (short)0;
            }
        }
    if (tid < 32) {
        bias_lds[tid]      = b_ih[j0 + tid] + b_hh[j0 + tid];               // r
        bias_lds[32 + tid] = b_ih[HID + j0 + tid] + b_hh[HID + j0 + tid];   // z
        bias_lds[64 + tid] = b_ih[2 * HID + j0 + tid];                      // n (x side)
        bias_lds[96 + tid] = b_hh[2 * HID + j0 + tid];                      // n (h side)
    }
    // ---- fused decode: 2 WGs per batch, 512 cols each; W_dec bf16-packed ----
    const int bdec  = Bg + (gs >> 1);
    const int qdec  = gs & 1;
    const int d_del = delays[bdec];
    const int odec  = tid & 31;
    const int jgd   = tid >> 5;         // 0..7 -> cols [jgd*64, +64)
    unsigned wdp[32];
    #pragma unroll
    for (int k = 0; k < 32; ++k) {
        float f0 = 0.f, f1 = 0.f;
        if (odec < NIN) {
            const float* wr = W_dec + (size_t)odec * HID + qdec * 512 + jgd * 64 + 2 * k;
            f0 = wr[0]; f1 = wr[1];
        }
        wdp[k] = (unsigned)f2bf(f0) | ((unsigned)f2bf(f1) << 16);
    }

    const int jl = l15;
    const int bl = kq * 4 + lhi;
    const int arow = Bg + l15;          // A-fragment row = batch-in-group
    const unsigned* ringdw = (const unsigned*)ring_hi;

    int* myflag = flags + blockIdx.x * 16;
    // consumer wave kq needs cols [256kq,+256) = producer WGs 8kq..8kq+7
    const int* pollflag = flags + (gb * 32 + kq * 8 + (lane & 7)) * 16;

    float hprev[2] = {0.f, 0.f};
    bool dead = false;

    __syncthreads();

    #pragma clang loop unroll(disable)
    for (int t = 0; t < T_STEPS + LAG; ++t) {
        const int target = (t < T_STEPS) ? t : T_STEPS;
        const int t_dec  = t - LAG;
        const int slot_prev = (t + RINGN - 1) & (RINGN - 1);

        // ---- (A) decode y-row load: data >=7 steps old, long visible
        unsigned ydw = 0;
        {
            const int tau = (t_dec < d_del) ? t_dec : (t_dec - d_del);
            if (t_dec >= 0) {
                const unsigned* yrow = ringdw
                    + ((size_t)((tau & (RINGN - 1)) * NBATCH + bdec)) * (HID / 2) + qdec * 256;
                ld_b32_sys(yrow + tid, ydw);
            }
        }
        // ---- (B) x fragments (wave 0): independent of h
        bf16x8 axH = {}, axL = {};
        if (t < T_STEPS && kq == 0) {
            const float* xr = x + ((size_t)arow * T_STEPS + t) * NIN;
            #pragma unroll
            for (int jj = 0; jj < 8; ++jj) {
                const int kk = lhi * 8 + jj;
                if (kk < NIN) {
                    float f = xr[kk];
                    unsigned short hi = f2bf(f);
                    axH[jj] = (short)hi;
                    axL[jj] = (short)f2bf(f - bf2f(hi));
                }
            }
        }
        __builtin_amdgcn_sched_barrier(0);   // compiler x-waits stay above

        // ---- (C) poll: lanes 0-7 watch this wave's 8 producer WGs
        if (target > 0 && !dead) {
            int iter = 0;
            for (;;) {
                int v = target;
                if (lane < 8) v = ld_flag_sys(pollflag);
                if (__all(v >= target)) break;
                if (++iter > (1 << 16)) { dead = true; break; }
            }
        }
        wait_vm0();   // free if poll ran; covers t==0 / y / x stragglers

        // ---- (D) issue 8 ring loads (K-quarter), x-MFMAs overlap under them
        u32x4 rawH[8];
        if (t < T_STEPS) {
            const unsigned short* aH = ring_hi + ((size_t)(slot_prev * NBATCH + arow)) * HID
                                     + kq * 256 + lhi * 8;
            #pragma unroll
            for (int c = 0; c < 8; ++c) ld_b128_sys(aH + c * 32, rawH[c]);
        }

        f32x4 z4 = {0.f, 0.f, 0.f, 0.f};
        f32x4 acc[3][2] = {{z4, z4}, {z4, z4}, {z4, z4}};
        f32x4 accx[2] = {z4, z4};

        if (t < T_STEPS) {
            if (kq == 0) {              // x-path: 12 MFMAs while ring loads fly
                #pragma unroll
                for (int ct = 0; ct < 2; ++ct) {
                    acc[0][ct] = __builtin_amdgcn_mfma_f32_16x16x32_bf16(axH, wXH[0][ct], acc[0][ct], 0, 0, 0);
                    acc[1][ct] = __builtin_amdgcn_mfma_f32_16x16x32_bf16(axH, wXH[1][ct], acc[1][ct], 0, 0, 0);
                    accx[ct]   = __builtin_amdgcn_mfma_f32_16x16x32_bf16(axH, wXH[2][ct], accx[ct], 0, 0, 0);
                    acc[0][ct] = __builtin_amdgcn_mfma_f32_16x16x32_bf16(axL, wXH[0][ct], acc[0][ct], 0, 0, 0);
                    acc[1][ct] = __builtin_amdgcn_mfma_f32_16x16x32_bf16(axL, wXH[1][ct], acc[1][ct], 0, 0, 0);
                    accx[ct]   = __builtin_amdgcn_mfma_f32_16x16x32_bf16(axL, wXH[2][ct], accx[ct], 0, 0, 0);
                }
            }
            wait_vm0();                 // the 8 h loads done
            #pragma unroll
            for (int c = 0; c < 8; ++c) {       // W . h : 48 MFMAs
                bf16x8 a = __builtin_bit_cast(bf16x8, rawH[c]);
                #pragma unroll
                for (int ct = 0; ct < 2; ++ct) {
                    acc[0][ct] = __builtin_amdgcn_mfma_f32_16x16x32_bf16(a, wHH[0][ct][c], acc[0][ct], 0, 0, 0);
                    acc[1][ct] = __builtin_amdgcn_mfma_f32_16x16x32_bf16(a, wHH[1][ct][c], acc[1][ct], 0, 0, 0);
                    acc[2][ct] = __builtin_amdgcn_mfma_f32_16x16x32_bf16(a, wHH[2][ct][c], acc[2][ct], 0, 0, 0);
                }
            }
            #pragma unroll
            for (int n = 0; n < 3; ++n)
                #pragma unroll
                for (int ct = 0; ct < 2; ++ct)
                    red[((n * 2 + ct) * 4 + kq) * 64 + lane] = acc[n][ct];
            if (kq == 0) {
                red[24 * 64 + lane] = accx[0];
                red[25 * 64 + lane] = accx[1];
            }
        } else {
            wait_vm0();                 // drain y loads in the tail steps
        }
        if (t_dec >= 0) {
            ylds[t & 1][2 * tid]     = bf2f((unsigned short)(ydw & 0xFFFFu));
            ylds[t & 1][2 * tid + 1] = bf2f((unsigned short)(ydw >> 16));
        }
        __syncthreads();   // sync1

        if (t < T_STEPS) {
            // per col-tile: reduce 4 K-quarter partials; C layout col=lane&15,
            // row=(lane>>4)*4+reg
            const float* redf = (const float*)red;
            const int ridx = (jl + 16 * (bl >> 2)) * 4 + (bl & 3);
            #pragma unroll
            for (int ct = 0; ct < 2; ++ct) {
                float gr = 0.f, gz = 0.f, gh_n = 0.f;
                #pragma unroll
                for (int w = 0; w < 4; ++w) {
                    gr   += redf[(((0 * 2 + ct) * 4 + w) * 64) * 4 + ridx];
                    gz   += redf[(((1 * 2 + ct) * 4 + w) * 64) * 4 + ridx];
                    gh_n += redf[(((2 * 2 + ct) * 4 + w) * 64) * 4 + ridx];
                }
                const float i_n = redf[((24 + ct) * 64) * 4 + ridx];
                const int jc = ct * 16 + jl;
                const float r  = 1.f / (1.f + __expf(-(gr + bias_lds[jc])));
                const float z  = 1.f / (1.f + __expf(-(gz + bias_lds[32 + jc])));
                const float nn = tanhf(i_n + bias_lds[64 + jc] + r * (gh_n + bias_lds[96 + jc]));
                const float hnew = (1.f - z) * nn + z * hprev[ct];
                hprev[ct] = hnew;
                // pack adjacent-j pair into one dword (even lanes store)
                const unsigned short hih = f2bf(hnew);
                const unsigned nhi = __shfl_xor((unsigned)hih, 1);
                if ((l15 & 1) == 0) {
                    const unsigned dhi = (unsigned)hih | (nhi << 16);
                    const int bg = Bg + bl;
                    unsigned* ph = (unsigned*)ring_hi
                        + ((size_t)((t & (RINGN - 1)) * NBATCH + bg)) * (HID / 2)
                        + ((j0 + jc) >> 1);
                    st_b32_sys(ph, dhi);
                }
            }
        }
        // decode MACs hide here (post-store, pre-drain)
        float pdec = 0.f;
        if (t_dec >= 0) {
            if (odec < NIN) {
                const float* yr = ylds[t & 1] + jgd * 64;
                #pragma unroll
                for (int k = 0; k < 32; ++k) {
                    const unsigned w2 = wdp[k];
                    pdec += yr[2 * k]     * bf2f((unsigned short)(w2 & 0xFFFFu))
                          + yr[2 * k + 1] * bf2f((unsigned short)(w2 >> 16));
                }
            }
            pdec += __shfl_xor(pdec, 32);   // fold the wave's two jgd halves
        }
        wait_vm0();        // drain own h stores to the coherent point
        __syncthreads();   // sync2: whole WG's h is globally visible

        if (t < T_STEPS && tid == 0 && !dead)
            st_b32_sys(myflag, (unsigned)(t + 1));

        // ---- tail (shadowed by other WGs' polls): decode atomics
        if (t_dec >= 0 && lane < 32 && odec < NIN)
            atomicAdd(out + ((size_t)bdec * T_STEPS + t_dec) * NIN + odec, pdec);
    }
}

__global__ void fill_out_kernel(float* __restrict__ out, const float* __restrict__ b_dec, int n)
{
    int idx = blockIdx.x * blockDim.x + threadIdx.x;
    if (idx < n) out[idx] = b_dec[idx % NIN];
}

extern "C" void kernel_launch(void* const* d_in, const int* in_sizes, int n_in,
                              void* d_out, int out_size, void* d_ws, size_t ws_size,
                              hipStream_t stream)
{
    (void)in_sizes; (void)n_in;
    const float* xx    = (const float*)d_in[0];
    const int*   dl    = (const int*)d_in[1];
    const float* W_ih  = (const float*)d_in[2];
    const float* W_hh  = (const float*)d_in[3];
    const float* b_ih  = (const float*)d_in[4];
    const float* b_hh  = (const float*)d_in[5];
    const float* W_dec = (const float*)d_in[6];
    const float* b_dec = (const float*)d_in[7];
    float* out = (float*)d_out;

    if (ws_size < WS_NEED) return;

    unsigned short* ring_hi = (unsigned short*)d_ws;
    int*            flags   = (int*)((char*)d_ws + RINGHI_BYTES);

    const size_t slot_bytes = (size_t)NBATCH * HID * 2;   // 128 KiB
    // zero h(-1) (ring slot 31) + flags -- contiguous tail region
    hipMemsetAsync((char*)d_ws + (size_t)(RINGN - 1) * slot_bytes, 0,
                   slot_bytes + FLAGS_BYTES, stream);

    fill_out_kernel<<<dim3((out_size + 255) / 256), dim3(256), 0, stream>>>(out, b_dec, out_size);

    void* args[] = {(void*)&xx, (void*)&dl, (void*)&W_ih, (void*)&W_hh, (void*)&b_ih,
                    (void*)&b_hh, (void*)&W_dec, (void*)&out, (void*)&ring_hi, (void*)&flags};
    hipError_t e = hipLaunchCooperativeKernel((void*)gru_persist, dim3(NWG), dim3(256),
                                              args, 0, stream);
    if (e != hipSuccess) {
        gru_persist<<<dim3(NWG), dim3(256), 0, stream>>>(xx, dl, W_ih, W_hh, b_ih, b_hh,
                                                         W_dec, out, ring_hi, flags);
    }
}

// Round 14
// 4132.495 us; speedup vs baseline: 1.6117x; 1.1427x over previous
//
#include <hip/hip_runtime.h>

typedef short bf16x8 __attribute__((ext_vector_type(8)));
typedef float f32x4 __attribute__((ext_vector_type(4)));
typedef unsigned u32x4 __attribute__((ext_vector_type(4)));

#define T_STEPS 1024
#define NBATCH  64
#define HID     1024
#define NIN     27
#define RINGN   32
#define LAG     8
#define BPG     16
#define NWG     256

#define RINGHI_BYTES ((size_t)RINGN * NBATCH * HID * 2)   // 4 MiB
#define FLAGS_INTS   (NWG * 16)                           // per-WG flags, 64B stride
#define FLAGS_BYTES  ((size_t)FLAGS_INTS * sizeof(int))   // 16 KiB
#define WS_NEED      (RINGHI_BYTES + FLAGS_BYTES)

__device__ __forceinline__ unsigned short f2bf(float f) {
    unsigned u = __float_as_uint(f);
    unsigned r = u + 0x7FFFu + ((u >> 16) & 1u);
    return (unsigned short)(r >> 16);
}
__device__ __forceinline__ float bf2f(unsigned short h) {
    return __uint_as_float(((unsigned)h) << 16);
}

// ---- system-coherent (cross-XCD) ops -- the R3-R5/R10-proven primitives ----
__device__ __forceinline__ void ld_b128_sys(const void* p, u32x4& v) {
    asm volatile("global_load_dwordx4 %0, %1, off sc0 sc1" : "=v"(v) : "v"(p));
}
__device__ __forceinline__ void ld_b32_sys(const void* p, unsigned& v) {
    asm volatile("global_load_dword %0, %1, off sc0 sc1" : "=v"(v) : "v"(p));
}
__device__ __forceinline__ int ld_flag_sys(const int* p) {
    int v;
    asm volatile("global_load_dword %0, %1, off sc0 sc1\n\ts_waitcnt vmcnt(0)"
                 : "=v"(v) : "v"(p) : "memory");
    return v;
}
__device__ __forceinline__ void st_b32_sys(void* p, unsigned v) {
    asm volatile("global_store_dword %0, %1, off sc0 sc1" :: "v"(p), "v"(v) : "memory");
}
__device__ __forceinline__ void wait_vm0() {
    asm volatile("s_waitcnt vmcnt(0)" ::: "memory");
    __builtin_amdgcn_sched_barrier(0);   // rule #18: pin consumers below the wait
}

// Persistent GRU (R10 structure + producer self-prefetch): 4 groups x 64 WGs.
// Group gb owns batches [16gb,16gb+16); WG gs owns hidden cols [16gs,16gs+16).
// W_hh slice (48x1024 bf16) register-resident. h carried EXACT in fp32 per
// thread; single bf16 ring feeds matmul + fused delayed decode. Poll: each
// consumer wave waits on exactly its 16 K-quarter producer WGs. After the flag
// release each producer READS BACK its 16 fresh lines (sc0sc1) to eat the HBM
// first-touch miss off the critical path and allocate the lines in the LLC.
__global__ __launch_bounds__(256, 1)
void gru_persist(const float* __restrict__ x,
                 const int* __restrict__ delays,
                 const float* __restrict__ W_ih,
                 const float* __restrict__ W_hh,
                 const float* __restrict__ b_ih,
                 const float* __restrict__ b_hh,
                 const float* __restrict__ W_dec,
                 float* __restrict__ out,
                 unsigned short* __restrict__ ring_hi,
                 int* __restrict__ flags)
{
    const int tid  = threadIdx.x;
    const int lane = tid & 63;
    const int kq   = tid >> 6;          // wave id = K-quarter (0..3)
    const int gb   = blockIdx.x >> 6;   // batch group (0..3)
    const int gs   = blockIdx.x & 63;   // j-slice (0..63)
    const int j0   = gs * 16;
    const int l15  = lane & 15;
    const int lhi  = lane >> 4;
    const int Bg   = gb * BPG;

    __shared__ f32x4 red[13 * 64];      // 12 = 3 gates x 4 waves, +1 = i_n (x-part)
    __shared__ float ylds[2][256];      // decode y quarter-row, parity-buffered
    __shared__ float bias_lds[64];

    // ---- persistent W_hh bf16 fragments: 3 gates x 8 K-chunks ----
    bf16x8 wHH[3][8];
    #pragma unroll
    for (int n = 0; n < 3; ++n) {
        const float* wrow = W_hh + (size_t)(n * HID + j0 + l15) * HID;
        #pragma unroll
        for (int c = 0; c < 8; ++c) {
            const float* wr = wrow + kq * 256 + c * 32 + lhi * 8;
            #pragma unroll
            for (int jj = 0; jj < 8; ++jj) wHH[n][c][jj] = (short)f2bf(wr[jj]);
        }
    }
    bf16x8 wXH[3];
    #pragma unroll
    for (int n = 0; n < 3; ++n) {
        const float* wrow = W_ih + (size_t)(n * HID + j0 + l15) * NIN;
        #pragma unroll
        for (int jj = 0; jj < 8; ++jj) {
            const int kk = lhi * 8 + jj;
            wXH[n][jj] = (kk < NIN) ? (short)f2bf(wrow[kk]) : (short)0;
        }
    }
    if (tid < 16) {
        bias_lds[tid]      = b_ih[j0 + tid] + b_hh[j0 + tid];               // r
        bias_lds[16 + tid] = b_ih[HID + j0 + tid] + b_hh[HID + j0 + tid];   // z
        bias_lds[32 + tid] = b_ih[2 * HID + j0 + tid];                      // n (x side)
        bias_lds[48 + tid] = b_hh[2 * HID + j0 + tid];                      // n (h side)
    }
    // ---- fused decode assignment ----
    const int bdec  = Bg + (gs >> 2);
    const int qdec  = gs & 3;
    const int d_del = delays[bdec];
    const int odec  = tid & 31;
    const int jgd   = tid >> 5;
    float wd[32];
    #pragma unroll
    for (int jj = 0; jj < 32; ++jj)
        wd[jj] = (odec < NIN) ? W_dec[(size_t)odec * HID + qdec * 256 + jgd * 32 + jj] : 0.f;

    const int jl = l15;
    const int bl = kq * 4 + lhi;
    const int arow = Bg + l15;          // A-fragment row = batch-in-group

    int* myflag = flags + (gb * 64 + gs) * 16;
    // consumer wave kq depends on producers gs' in [16kq, 16kq+16)
    const int* pollflag = flags + (gb * 64 + kq * 16 + l15) * 16;

    float hprev = 0.f;
    bool dead = false;

    __syncthreads();

    #pragma clang loop unroll(disable)
    for (int t = 0; t < T_STEPS + LAG; ++t) {
        const int target = (t < T_STEPS) ? t : T_STEPS;
        const int t_dec  = t - LAG;
        const int slot_prev = (t + RINGN - 1) & (RINGN - 1);

        // ---- (A) decode y-row load: data >=7 steps old, long visible
        unsigned ydw = 0;
        if (t_dec >= 0 && tid < 128) {
            const int tau = (t_dec < d_del) ? t_dec : (t_dec - d_del);
            const unsigned* yrow = (const unsigned*)(ring_hi
                + ((size_t)((tau & (RINGN - 1)) * NBATCH + bdec)) * HID + qdec * 256);
            ld_b32_sys(yrow + tid, ydw);
        }
        // ---- (B) x fragments (wave 0): independent of h, built during the wait
        bf16x8 axH = {}, axL = {};
        if (t < T_STEPS && kq == 0) {
            const float* xr = x + ((size_t)arow * T_STEPS + t) * NIN;
            #pragma unroll
            for (int jj = 0; jj < 8; ++jj) {
                const int kk = lhi * 8 + jj;
                if (kk < NIN) {
                    float f = xr[kk];
                    unsigned short hi = f2bf(f);
                    axH[jj] = (short)hi;
                    axL[jj] = (short)f2bf(f - bf2f(hi));
                }
            }
        }
        __builtin_amdgcn_sched_barrier(0);   // compiler x-waits stay above

        // ---- (C) poll: lanes 0-15 watch this wave's 16 producer WGs
        if (target > 0 && !dead) {
            int iter = 0;
            for (;;) {
                int v = target;
                if (lane < 16) v = ld_flag_sys(pollflag);
                if (__all(v >= target)) break;
                if (++iter > (1 << 16)) { dead = true; break; }
            }
        }
        wait_vm0();   // free if poll ran; covers t==0 / y / x stragglers

        // ---- (D) issue 8 ring loads, overlap x-MFMAs under them
        u32x4 rawH[8];
        if (t < T_STEPS) {
            const unsigned short* aH = ring_hi + ((size_t)(slot_prev * NBATCH + arow)) * HID
                                     + kq * 256 + lhi * 8;
            #pragma unroll
            for (int c = 0; c < 8; ++c) ld_b128_sys(aH + c * 32, rawH[c]);
        }

        f32x4 z4 = {0.f, 0.f, 0.f, 0.f};
        f32x4 acc0 = z4, acc1 = z4, acc2 = z4, acc2x = z4;

        if (t < T_STEPS) {
            if (kq == 0) {              // x-path MFMAs while ring loads fly
                acc0  = __builtin_amdgcn_mfma_f32_16x16x32_bf16(axH, wXH[0], acc0, 0, 0, 0);
                acc1  = __builtin_amdgcn_mfma_f32_16x16x32_bf16(axH, wXH[1], acc1, 0, 0, 0);
                acc2x = __builtin_amdgcn_mfma_f32_16x16x32_bf16(axH, wXH[2], acc2x, 0, 0, 0);
                acc0  = __builtin_amdgcn_mfma_f32_16x16x32_bf16(axL, wXH[0], acc0, 0, 0, 0);
                acc1  = __builtin_amdgcn_mfma_f32_16x16x32_bf16(axL, wXH[1], acc1, 0, 0, 0);
                acc2x = __builtin_amdgcn_mfma_f32_16x16x32_bf16(axL, wXH[2], acc2x, 0, 0, 0);
            }
            wait_vm0();                 // the 8 h loads done
            #pragma unroll
            for (int c = 0; c < 8; ++c) {       // W . h
                bf16x8 a = __builtin_bit_cast(bf16x8, rawH[c]);
                acc0 = __builtin_amdgcn_mfma_f32_16x16x32_bf16(a, wHH[0][c], acc0, 0, 0, 0);
                acc1 = __builtin_amdgcn_mfma_f32_16x16x32_bf16(a, wHH[1][c], acc1, 0, 0, 0);
                acc2 = __builtin_amdgcn_mfma_f32_16x16x32_bf16(a, wHH[2][c], acc2, 0, 0, 0);
            }
            red[(0 * 4 + kq) * 64 + lane] = acc0;
            red[(1 * 4 + kq) * 64 + lane] = acc1;
            red[(2 * 4 + kq) * 64 + lane] = acc2;
            if (kq == 0) red[12 * 64 + lane] = acc2x;
        } else {
            wait_vm0();                 // drain y loads in the tail steps
        }
        if (t_dec >= 0 && tid < 128) {
            ylds[t & 1][2 * tid]     = bf2f((unsigned short)(ydw & 0xFFFFu));
            ylds[t & 1][2 * tid + 1] = bf2f((unsigned short)(ydw >> 16));
        }
        __syncthreads();   // sync1

        if (t < T_STEPS) {
            // reduce 4 K-quarter partials; C layout: col=lane&15, row=(lane>>4)*4+reg
            const float* redf = (const float*)red;
            const int ridx = (jl + 16 * (bl >> 2)) * 4 + (bl & 3);
            float gr = 0.f, gz = 0.f, gh_n = 0.f;
            #pragma unroll
            for (int w = 0; w < 4; ++w) {
                gr   += redf[((0 * 4 + w) * 64) * 4 + ridx];
                gz   += redf[((1 * 4 + w) * 64) * 4 + ridx];
                gh_n += redf[((2 * 4 + w) * 64) * 4 + ridx];
            }
            const float i_n = redf[(12 * 64) * 4 + ridx];
            const float r  = 1.f / (1.f + __expf(-(gr + bias_lds[jl])));
            const float z  = 1.f / (1.f + __expf(-(gz + bias_lds[16 + jl])));
            const float nn = tanhf(i_n + bias_lds[32 + jl] + r * (gh_n + bias_lds[48 + jl]));
            const float hnew = (1.f - z) * nn + z * hprev;
            hprev = hnew;
            // pack adjacent-j pair into one dword (even lanes store)
            const unsigned short hih = f2bf(hnew);
            const unsigned nhi = __shfl_xor((unsigned)hih, 1);
            if ((l15 & 1) == 0) {
                const unsigned dhi = (unsigned)hih | (nhi << 16);
                const int bg = Bg + bl;
                unsigned short* ph = ring_hi
                    + ((size_t)((t & (RINGN - 1)) * NBATCH + bg)) * HID + j0 + jl;
                st_b32_sys(ph, dhi);
            }
        }
        // decode MACs hide here (different waves / same waves post-store)
        float pdec = 0.f;
        if (t_dec >= 0) {
            if (odec < NIN) {
                const float* yrow = ylds[t & 1] + jgd * 32;
                #pragma unroll
                for (int k = 0; k < 32; ++k) pdec += yrow[k] * wd[k];
            }
            pdec += __shfl_xor(pdec, 32);   // fold the wave's two j-groups
        }
        wait_vm0();        // drain own h stores to the coherent point
        __syncthreads();   // sync2: whole WG's h is globally visible

        if (t < T_STEPS && tid == 0 && !dead)
            st_b32_sys(myflag, (unsigned)(t + 1));

        // ---- self-prefetch (shadow): read back this WG's 16 fresh lines so
        // the HBM first-touch miss is paid HERE, not on a consumer's critical
        // path; the line allocates in the LLC for the 64 consumers.
        if (t < T_STEPS && tid < 16) {
            const unsigned* pf = (const unsigned*)ring_hi
                + ((size_t)((t & (RINGN - 1)) * NBATCH + Bg + tid)) * (HID / 2) + (j0 >> 1);
            unsigned dummy;
            ld_b32_sys(pf, dummy);   // drained by next step's poll vmcnt(0)
        }

        // ---- tail (shadowed by other WGs' polls): decode atomics
        if (t_dec >= 0 && lane < 32 && odec < NIN)
            atomicAdd(out + ((size_t)bdec * T_STEPS + t_dec) * NIN + odec, pdec);
    }
}

__global__ void fill_out_kernel(float* __restrict__ out, const float* __restrict__ b_dec, int n)
{
    int idx = blockIdx.x * blockDim.x + threadIdx.x;
    if (idx < n) out[idx] = b_dec[idx % NIN];
}

extern "C" void kernel_launch(void* const* d_in, const int* in_sizes, int n_in,
                              void* d_out, int out_size, void* d_ws, size_t ws_size,
                              hipStream_t stream)
{
    (void)in_sizes; (void)n_in;
    const float* xx    = (const float*)d_in[0];
    const int*   dl    = (const int*)d_in[1];
    const float* W_ih  = (const float*)d_in[2];
    const float* W_hh  = (const float*)d_in[3];
    const float* b_ih  = (const float*)d_in[4];
    const float* b_hh  = (const float*)d_in[5];
    const float* W_dec = (const float*)d_in[6];
    const float* b_dec = (const float*)d_in[7];
    float* out = (float*)d_out;

    if (ws_size < WS_NEED) return;

    unsigned short* ring_hi = (unsigned short*)d_ws;
    int*            flags   = (int*)((char*)d_ws + RINGHI_BYTES);

    const size_t slot_bytes = (size_t)NBATCH * HID * 2;   // 128 KiB
    // zero h(-1) (ring slot 31) + flags -- contiguous tail region
    hipMemsetAsync((char*)d_ws + (size_t)(RINGN - 1) * slot_bytes, 0,
                   slot_bytes + FLAGS_BYTES, stream);

    fill_out_kernel<<<dim3((out_size + 255) / 256), dim3(256), 0, stream>>>(out, b_dec, out_size);

    void* args[] = {(void*)&xx, (void*)&dl, (void*)&W_ih, (void*)&W_hh, (void*)&b_ih,
                    (void*)&b_hh, (void*)&W_dec, (void*)&out, (void*)&ring_hi, (void*)&flags};
    hipError_t e = hipLaunchCooperativeKernel((void*)gru_persist, dim3(NWG), dim3(256),
                                              args, 0, stream);
    if (e != hipSuccess) {
        gru_persist<<<dim3(NWG), dim3(256), 0, stream>>>(xx, dl, W_ih, W_hh, b_ih, b_hh,
                                                         W_dec, out, ring_hi, flags);
    }
}

// Round 15
// 3991.191 us; speedup vs baseline: 1.6688x; 1.0354x over previous
//
#include <hip/hip_runtime.h>

typedef short bf16x8 __attribute__((ext_vector_type(8)));
typedef float f32x4 __attribute__((ext_vector_type(4)));
typedef unsigned u32x4 __attribute__((ext_vector_type(4)));

#define T_STEPS 1024
#define NBATCH  64
#define HID     1024
#define NIN     27
#define RINGN   32      // small-ring slot count (fallback path)
#define NSLOT   1025    // big-ring: one slot per step + h(-1); no address reuse
#define LAG     8
#define BPG     16
#define NWG     256

#define SLOT_BYTES   ((size_t)NBATCH * HID * 2)              // 128 KiB
#define FLAGS_INTS   (NWG * 16)                              // per-WG flags, 64B stride
#define FLAGS_BYTES  ((size_t)FLAGS_INTS * sizeof(int))      // 16 KiB
#define WS_SMALL     ((size_t)RINGN * SLOT_BYTES + FLAGS_BYTES)   // 4.02 MiB
#define WS_BIG       ((size_t)NSLOT * SLOT_BYTES + FLAGS_BYTES)   // ~134.4 MiB

__device__ __forceinline__ unsigned short f2bf(float f) {
    unsigned u = __float_as_uint(f);
    unsigned r = u + 0x7FFFu + ((u >> 16) & 1u);
    return (unsigned short)(r >> 16);
}
__device__ __forceinline__ float bf2f(unsigned short h) {
    return __uint_as_float(((unsigned)h) << 16);
}

// ---- system-coherent (cross-XCD) ops -- the R3-R5/R10-proven primitives ----
__device__ __forceinline__ void ld_b128_sys(const void* p, u32x4& v) {
    asm volatile("global_load_dwordx4 %0, %1, off sc0 sc1" : "=v"(v) : "v"(p));
}
__device__ __forceinline__ void ld_b32_sys(const void* p, unsigned& v) {
    asm volatile("global_load_dword %0, %1, off sc0 sc1" : "=v"(v) : "v"(p));
}
__device__ __forceinline__ int ld_flag_sys(const int* p) {
    int v;
    asm volatile("global_load_dword %0, %1, off sc0 sc1\n\ts_waitcnt vmcnt(0)"
                 : "=v"(v) : "v"(p) : "memory");
    return v;
}
__device__ __forceinline__ void st_b32_sys(void* p, unsigned v) {
    asm volatile("global_store_dword %0, %1, off sc0 sc1" :: "v"(p), "v"(v) : "memory");
}
__device__ __forceinline__ void wait_vm0() {
    asm volatile("s_waitcnt vmcnt(0)" ::: "memory");
    __builtin_amdgcn_sched_barrier(0);   // rule #18: pin consumers below the wait
}

// Persistent GRU (R10 structure; template BIG selects the no-reuse ring):
// 4 groups x 64 WGs. Group gb owns batches [16gb,16gb+16); WG gs owns hidden
// cols [16gs,16gs+16). W_hh slice (48x1024 bf16) register-resident; h carried
// EXACT in fp32 per thread; bf16 ring doubles as y_hat history for decode.
// BIG=0: 32-slot ring, consumers MUST read uncached (sc0sc1) -- addresses
//        recycle every 32 steps and per-XCD L2s would serve stale lines.
// BIG=1: slot(t)=t+1, no address ever reused within a dispatch -> consumers
//        use PLAIN CACHED loads; 8 WGs per XCD share each slot line in L2.
//        Producer side identical (sc0sc1 write-through + drain + flag).
template<bool BIG>
__global__ __launch_bounds__(256, 1)
void gru_persist(const float* __restrict__ x,
                 const int* __restrict__ delays,
                 const float* __restrict__ W_ih,
                 const float* __restrict__ W_hh,
                 const float* __restrict__ b_ih,
                 const float* __restrict__ b_hh,
                 const float* __restrict__ W_dec,
                 float* __restrict__ out,
                 unsigned short* __restrict__ ring_hi,
                 int* __restrict__ flags)
{
    const int tid  = threadIdx.x;
    const int lane = tid & 63;
    const int kq   = tid >> 6;          // wave id = K-quarter (0..3)
    const int gb   = blockIdx.x >> 6;   // batch group (0..3)
    const int gs   = blockIdx.x & 63;   // j-slice (0..63)
    const int j0   = gs * 16;
    const int l15  = lane & 15;
    const int lhi  = lane >> 4;
    const int Bg   = gb * BPG;

    __shared__ f32x4 red[13 * 64];      // 12 = 3 gates x 4 waves, +1 = i_n (x-part)
    __shared__ float ylds[2][256];      // decode y quarter-row, parity-buffered
    __shared__ float bias_lds[64];

    // ---- persistent W_hh bf16 fragments: 3 gates x 8 K-chunks ----
    bf16x8 wHH[3][8];
    #pragma unroll
    for (int n = 0; n < 3; ++n) {
        const float* wrow = W_hh + (size_t)(n * HID + j0 + l15) * HID;
        #pragma unroll
        for (int c = 0; c < 8; ++c) {
            const float* wr = wrow + kq * 256 + c * 32 + lhi * 8;
            #pragma unroll
            for (int jj = 0; jj < 8; ++jj) wHH[n][c][jj] = (short)f2bf(wr[jj]);
        }
    }
    bf16x8 wXH[3];
    #pragma unroll
    for (int n = 0; n < 3; ++n) {
        const float* wrow = W_ih + (size_t)(n * HID + j0 + l15) * NIN;
        #pragma unroll
        for (int jj = 0; jj < 8; ++jj) {
            const int kk = lhi * 8 + jj;
            wXH[n][jj] = (kk < NIN) ? (short)f2bf(wrow[kk]) : (short)0;
        }
    }
    if (tid < 16) {
        bias_lds[tid]      = b_ih[j0 + tid] + b_hh[j0 + tid];               // r
        bias_lds[16 + tid] = b_ih[HID + j0 + tid] + b_hh[HID + j0 + tid];   // z
        bias_lds[32 + tid] = b_ih[2 * HID + j0 + tid];                      // n (x side)
        bias_lds[48 + tid] = b_hh[2 * HID + j0 + tid];                      // n (h side)
    }
    // ---- fused decode assignment ----
    const int bdec  = Bg + (gs >> 2);
    const int qdec  = gs & 3;
    const int d_del = delays[bdec];
    const int odec  = tid & 31;
    const int jgd   = tid >> 5;
    float wd[32];
    #pragma unroll
    for (int jj = 0; jj < 32; ++jj)
        wd[jj] = (odec < NIN) ? W_dec[(size_t)odec * HID + qdec * 256 + jgd * 32 + jj] : 0.f;

    const int jl = l15;
    const int bl = kq * 4 + lhi;
    const int arow = Bg + l15;          // A-fragment row = batch-in-group

    int* myflag = flags + (gb * 64 + gs) * 16;
    // consumer wave kq depends on producers gs' in [16kq, 16kq+16)
    const int* pollflag = flags + (gb * 64 + kq * 16 + l15) * 16;

    float hprev = 0.f;
    bool dead = false;

    __syncthreads();

    #pragma clang loop unroll(disable)
    for (int t = 0; t < T_STEPS + LAG; ++t) {
        const int target = (t < T_STEPS) ? t : T_STEPS;
        const int t_dec  = t - LAG;
        // slot holding h(t-1):  BIG: t (h(-1) in slot 0)   small: (t-1)&31
        const size_t slot_prev = BIG ? (size_t)t : (size_t)((t + RINGN - 1) & (RINGN - 1));
        const size_t slot_wr   = BIG ? (size_t)(t + 1) : (size_t)(t & (RINGN - 1));

        // ---- (A) decode y-row load: data >=7 steps old, long visible
        unsigned ydw = 0;
        if (t_dec >= 0 && tid < 128) {
            const int tau = (t_dec < d_del) ? t_dec : (t_dec - d_del);
            const size_t slot_y = BIG ? (size_t)(tau + 1) : (size_t)(tau & (RINGN - 1));
            const unsigned* yrow = (const unsigned*)(ring_hi
                + (slot_y * NBATCH + bdec) * HID + qdec * 256);
            if (BIG) ydw = yrow[tid];           // cached: address never re-written
            else     ld_b32_sys(yrow + tid, ydw);
        }
        // ---- (B) x fragments (wave 0): independent of h, built during the wait
        bf16x8 axH = {}, axL = {};
        if (t < T_STEPS && kq == 0) {
            const float* xr = x + ((size_t)arow * T_STEPS + t) * NIN;
            #pragma unroll
            for (int jj = 0; jj < 8; ++jj) {
                const int kk = lhi * 8 + jj;
                if (kk < NIN) {
                    float f = xr[kk];
                    unsigned short hi = f2bf(f);
                    axH[jj] = (short)hi;
                    axL[jj] = (short)f2bf(f - bf2f(hi));
                }
            }
        }
        __builtin_amdgcn_sched_barrier(0);   // compiler x-waits stay above

        // ---- (C) poll: lanes 0-15 watch this wave's 16 producer WGs
        if (target > 0 && !dead) {
            int iter = 0;
            for (;;) {
                int v = target;
                if (lane < 16) v = ld_flag_sys(pollflag);
                if (__all(v >= target)) break;
                if (++iter > (1 << 16)) { dead = true; break; }
            }
        }
        wait_vm0();   // free if poll ran; covers t==0 / y / x stragglers

        // ---- (D) issue 8 ring loads, overlap x-MFMAs under them
        u32x4 rawH[8];
        if (t < T_STEPS) {
            const unsigned short* aH = ring_hi + (slot_prev * NBATCH + arow) * HID
                                     + kq * 256 + lhi * 8;
            if (BIG) {
                // plain cached loads: fresh addresses, L2-shared across the
                // 8 group-WGs on each XCD; compiler tracks the waits
                #pragma unroll
                for (int c = 0; c < 8; ++c) rawH[c] = *(const u32x4*)(aH + c * 32);
            } else {
                #pragma unroll
                for (int c = 0; c < 8; ++c) ld_b128_sys(aH + c * 32, rawH[c]);
            }
        }

        f32x4 z4 = {0.f, 0.f, 0.f, 0.f};
        f32x4 acc0 = z4, acc1 = z4, acc2 = z4, acc2x = z4;

        if (t < T_STEPS) {
            if (kq == 0) {              // x-path MFMAs while ring loads fly
                acc0  = __builtin_amdgcn_mfma_f32_16x16x32_bf16(axH, wXH[0], acc0, 0, 0, 0);
                acc1  = __builtin_amdgcn_mfma_f32_16x16x32_bf16(axH, wXH[1], acc1, 0, 0, 0);
                acc2x = __builtin_amdgcn_mfma_f32_16x16x32_bf16(axH, wXH[2], acc2x, 0, 0, 0);
                acc0  = __builtin_amdgcn_mfma_f32_16x16x32_bf16(axL, wXH[0], acc0, 0, 0, 0);
                acc1  = __builtin_amdgcn_mfma_f32_16x16x32_bf16(axL, wXH[1], acc1, 0, 0, 0);
                acc2x = __builtin_amdgcn_mfma_f32_16x16x32_bf16(axL, wXH[2], acc2x, 0, 0, 0);
            }
            if (!BIG) wait_vm0();       // asm loads need the manual drain
            #pragma unroll
            for (int c = 0; c < 8; ++c) {       // W . h
                bf16x8 a = __builtin_bit_cast(bf16x8, rawH[c]);
                acc0 = __builtin_amdgcn_mfma_f32_16x16x32_bf16(a, wHH[0][c], acc0, 0, 0, 0);
                acc1 = __builtin_amdgcn_mfma_f32_16x16x32_bf16(a, wHH[1][c], acc1, 0, 0, 0);
                acc2 = __builtin_amdgcn_mfma_f32_16x16x32_bf16(a, wHH[2][c], acc2, 0, 0, 0);
            }
            red[(0 * 4 + kq) * 64 + lane] = acc0;
            red[(1 * 4 + kq) * 64 + lane] = acc1;
            red[(2 * 4 + kq) * 64 + lane] = acc2;
            if (kq == 0) red[12 * 64 + lane] = acc2x;
        } else {
            wait_vm0();                 // drain y loads in the tail steps
        }
        if (t_dec >= 0 && tid < 128) {
            ylds[t & 1][2 * tid]     = bf2f((unsigned short)(ydw & 0xFFFFu));
            ylds[t & 1][2 * tid + 1] = bf2f((unsigned short)(ydw >> 16));
        }
        __syncthreads();   // sync1

        if (t < T_STEPS) {
            // reduce 4 K-quarter partials; C layout: col=lane&15, row=(lane>>4)*4+reg
            const float* redf = (const float*)red;
            const int ridx = (jl + 16 * (bl >> 2)) * 4 + (bl & 3);
            float gr = 0.f, gz = 0.f, gh_n = 0.f;
            #pragma unroll
            for (int w = 0; w < 4; ++w) {
                gr   += redf[((0 * 4 + w) * 64) * 4 + ridx];
                gz   += redf[((1 * 4 + w) * 64) * 4 + ridx];
                gh_n += redf[((2 * 4 + w) * 64) * 4 + ridx];
            }
            const float i_n = redf[(12 * 64) * 4 + ridx];
            const float r  = 1.f / (1.f + __expf(-(gr + bias_lds[jl])));
            const float z  = 1.f / (1.f + __expf(-(gz + bias_lds[16 + jl])));
            const float nn = tanhf(i_n + bias_lds[32 + jl] + r * (gh_n + bias_lds[48 + jl]));
            const float hnew = (1.f - z) * nn + z * hprev;
            hprev = hnew;
            // pack adjacent-j pair into one dword (even lanes store)
            const unsigned short hih = f2bf(hnew);
            const unsigned nhi = __shfl_xor((unsigned)hih, 1);
            if ((l15 & 1) == 0) {
                const unsigned dhi = (unsigned)hih | (nhi << 16);
                const int bg = Bg + bl;
                unsigned short* ph = ring_hi + (slot_wr * NBATCH + bg) * HID + j0 + jl;
                st_b32_sys(ph, dhi);   // sc0sc1 write-through: visible at LLC
            }
        }
        // decode MACs hide here (different waves / same waves post-store)
        float pdec = 0.f;
        if (t_dec >= 0) {
            if (odec < NIN) {
                const float* yrow = ylds[t & 1] + jgd * 32;
                #pragma unroll
                for (int k = 0; k < 32; ++k) pdec += yrow[k] * wd[k];
            }
            pdec += __shfl_xor(pdec, 32);   // fold the wave's two j-groups
        }
        wait_vm0();        // drain own h stores to the coherent point
        __syncthreads();   // sync2: whole WG's h is globally visible

        if (t < T_STEPS && tid == 0 && !dead)
            st_b32_sys(myflag, (unsigned)(t + 1));

        // ---- tail (shadowed by other WGs' polls): decode atomics
        if (t_dec >= 0 && lane < 32 && odec < NIN)
            atomicAdd(out + ((size_t)bdec * T_STEPS + t_dec) * NIN + odec, pdec);
    }
}

__global__ void fill_out_kernel(float* __restrict__ out, const float* __restrict__ b_dec, int n)
{
    int idx = blockIdx.x * blockDim.x + threadIdx.x;
    if (idx < n) out[idx] = b_dec[idx % NIN];
}

extern "C" void kernel_launch(void* const* d_in, const int* in_sizes, int n_in,
                              void* d_out, int out_size, void* d_ws, size_t ws_size,
                              hipStream_t stream)
{
    (void)in_sizes; (void)n_in;
    const float* xx    = (const float*)d_in[0];
    const int*   dl    = (const int*)d_in[1];
    const float* W_ih  = (const float*)d_in[2];
    const float* W_hh  = (const float*)d_in[3];
    const float* b_ih  = (const float*)d_in[4];
    const float* b_hh  = (const float*)d_in[5];
    const float* W_dec = (const float*)d_in[6];
    const float* b_dec = (const float*)d_in[7];
    float* out = (float*)d_out;

    if (ws_size < WS_SMALL) return;

    unsigned short* ring_hi = (unsigned short*)d_ws;
    const bool big = (ws_size >= WS_BIG);

    fill_out_kernel<<<dim3((out_size + 255) / 256), dim3(256), 0, stream>>>(out, b_dec, out_size);

    if (big) {
        // no-reuse ring: slot(t)=t+1; h(-1) = slot 0 (zeroed each launch)
        int* flags = (int*)((char*)d_ws + (size_t)NSLOT * SLOT_BYTES);
        hipMemsetAsync(d_ws, 0, SLOT_BYTES, stream);
        hipMemsetAsync(flags, 0, FLAGS_BYTES, stream);
        void* args[] = {(void*)&xx, (void*)&dl, (void*)&W_ih, (void*)&W_hh, (void*)&b_ih,
                        (void*)&b_hh, (void*)&W_dec, (void*)&out, (void*)&ring_hi, (void*)&flags};
        hipError_t e = hipLaunchCooperativeKernel((void*)gru_persist<true>, dim3(NWG), dim3(256),
                                                  args, 0, stream);
        if (e != hipSuccess)
            gru_persist<true><<<dim3(NWG), dim3(256), 0, stream>>>(
                xx, dl, W_ih, W_hh, b_ih, b_hh, W_dec, out, ring_hi, flags);
    } else {
        // fallback: exact R10 (proven 3965 us)
        int* flags = (int*)((char*)d_ws + (size_t)RINGN * SLOT_BYTES);
        hipMemsetAsync((char*)d_ws + (size_t)(RINGN - 1) * SLOT_BYTES, 0,
                       SLOT_BYTES + FLAGS_BYTES, stream);
        void* args[] = {(void*)&xx, (void*)&dl, (void*)&W_ih, (void*)&W_hh, (void*)&b_ih,
                        (void*)&b_hh, (void*)&W_dec, (void*)&out, (void*)&ring_hi, (void*)&flags};
        hipError_t e = hipLaunchCooperativeKernel((void*)gru_persist<false>, dim3(NWG), dim3(256),
                                                  args, 0, stream);
        if (e != hipSuccess)
            gru_persist<false><<<dim3(NWG), dim3(256), 0, stream>>>(
                xx, dl, W_ih, W_hh, b_ih, b_hh, W_dec, out, ring_hi, flags);
    }
}